// Round 1
// baseline (592.333 us; speedup 1.0000x reference)
//
#include <hip/hip_runtime.h>
#include <math.h>

// Problem constants (from setup_inputs): B=64, S=4096, D=128.
#define NB 64
#define NS 4096
#define ND 128
#define NPTS (NB * NS)          // 262144 points
#define PPB 256                 // points per block in K3/K5
#define NBLK (NPTS / PPB)       // 1024 blocks
#define EPSV 1e-5f
#define CLAMPV 1e-8f
#define MAXEUC 32.0f

__device__ __forceinline__ float wred(float v) {
#pragma unroll
    for (int o = 32; o > 0; o >>= 1) v += __shfl_xor(v, o, 64);
    return v;
}

// ---------------- K1: partial sums of x over S (per b, per chunk of 512 rows)
__global__ __launch_bounds__(256) void k1(const float4* __restrict__ x4,
                                          float4* __restrict__ part1) {
    const int b = blockIdx.x >> 3;
    const int c = blockIdx.x & 7;
    const int d4 = threadIdx.x & 31;   // float4 index within the 128-dim point
    const int g  = threadIdx.x >> 5;   // 8 row-groups
    const int srow = c * 512 + g;
    const float4* p = x4 + ((long long)b * NS + srow) * 32 + d4;
    float4 acc = make_float4(0.f, 0.f, 0.f, 0.f);
#pragma unroll 4
    for (int i = 0; i < 64; ++i) {
        float4 v = p[(long long)i * 8 * 32];
        acc.x += v.x; acc.y += v.y; acc.z += v.z; acc.w += v.w;
    }
    __shared__ float4 red[256];
    red[threadIdx.x] = acc;
    __syncthreads();
    if (threadIdx.x < 32) {
        float4 r = red[threadIdx.x];
#pragma unroll
        for (int gg = 1; gg < 8; ++gg) {
            float4 v = red[gg * 32 + threadIdx.x];
            r.x += v.x; r.y += v.y; r.z += v.z; r.w += v.w;
        }
        part1[(long long)blockIdx.x * 32 + threadIdx.x] = r;
    }
}

// ---------------- K2: double Lorentz centroid -> mean (D,)
__global__ __launch_bounds__(256) void k2(const float* __restrict__ part1,
                                          float* __restrict__ meanG) {
    __shared__ float avgL[NB * ND];
    __shared__ float avg2L[ND];
    __shared__ float denomS;
    const int t = threadIdx.x;
    // avg over S
    for (int idx = t; idx < NB * ND; idx += 256) {
        int b = idx >> 7, d = idx & 127;
        float s = 0.f;
#pragma unroll
        for (int c = 0; c < 8; ++c) s += part1[((b << 3) + c) * ND + d];
        avgL[idx] = s * (1.0f / (float)NS);
    }
    __syncthreads();
    // normalize each of the 64 row-centroids (wave-per-b)
    const int w = t >> 6, l = t & 63;
    for (int b = w; b < NB; b += 4) {
        float a0 = avgL[b * ND + l];
        float a1 = avgL[b * ND + 64 + l];
        float a00 = avgL[b * ND];           // time component (before overwrite)
        float s = wred(a0 * a0 + a1 * a1);  // sum of squares over all d
        float denom = sqrtf(fmaxf(2.f * a00 * a00 - s, CLAMPV)); // sqrt(-<a,a>_L)
        avgL[b * ND + l] = a0 / denom;
        avgL[b * ND + 64 + l] = a1 / denom;
    }
    __syncthreads();
    // avg over B
    if (t < ND) {
        float s = 0.f;
        for (int b = 0; b < NB; ++b) s += avgL[b * ND + t];
        avg2L[t] = s * (1.0f / (float)NB);
    }
    __syncthreads();
    if (w == 0) {
        float a0 = avg2L[l], a1 = avg2L[l + 64];
        float s = wred(a0 * a0 + a1 * a1);
        float a00 = avg2L[0];
        float denom = sqrtf(fmaxf(2.f * a00 * a00 - s, CLAMPV));
        if (l == 0) denomS = denom;
    }
    __syncthreads();
    if (t < ND) meanG[t] = avg2L[t] / denomS;
}

// shared compute: logmap at mean + parallel transport back to origin.
// lane l holds features (2l, 2l+1) of a point. Returns t0,t1.
__device__ __forceinline__ void tangent_at_origin(float2 xv, float2 m, float m0,
                                                  int l, float& t0, float& t1) {
    float dot = wred(xv.x * m.x + xv.y * m.y);      // <x, mean> euclid
    float x0 = __shfl(xv.x, 0, 64);
    float alpha = fmaxf(2.f * x0 * m0 - dot, 1.0f + 1e-7f);  // -<mean,x>_L clipped
    float u0 = xv.x - alpha * m.x;
    float u1 = xv.y - alpha * m.y;
    float uu = wred(u0 * u0 + u1 * u1);
    float ut = __shfl(u0, 0, 64);
    uu -= 2.f * ut * ut;                            // <u,u>_L
    float unorm = sqrtf(fmaxf(uu, CLAMPV));
    float fac = acoshf(alpha) / unorm;
    t0 = fac * u0;
    t1 = fac * u1;
    // transp0back: coef = -v0/(1+mean0); v += coef * (mean + origin)
    float vt = __shfl(t0, 0, 64);
    float coef = -vt / (1.f + m0);
    t0 += coef * (m.x + ((l == 0) ? 1.f : 0.f));
    t1 += coef * m.y;
}

// ---------------- K3: per-feature sum and sumsq of x_T (per-block partials)
__global__ __launch_bounds__(256) void k3(const float2* __restrict__ x2,
                                          const float* __restrict__ meanG,
                                          float* __restrict__ part3) {
    const int l = threadIdx.x & 63;
    const int w = threadIdx.x >> 6;
    const float2 m = ((const float2*)meanG)[l];
    const float m0 = meanG[0];
    float s0 = 0.f, s1 = 0.f, q0 = 0.f, q1 = 0.f;
    const long long base = (long long)blockIdx.x * PPB;
    for (int i = 0; i < PPB / 4; ++i) {
        long long p = base + (long long)i * 4 + w;
        float2 xv = x2[p * 64 + l];
        float t0, t1;
        tangent_at_origin(xv, m, m0, l, t0, t1);
        s0 += t0; s1 += t1;
        q0 += t0 * t0; q1 += t1 * t1;
    }
    __shared__ float ls[4 * ND];
    __shared__ float lq[4 * ND];
    ls[w * ND + 2 * l] = s0; ls[w * ND + 2 * l + 1] = s1;
    lq[w * ND + 2 * l] = q0; lq[w * ND + 2 * l + 1] = q1;
    __syncthreads();
    if (threadIdx.x < ND) {
        int d = threadIdx.x;
        float S = ls[d] + ls[ND + d] + ls[2 * ND + d] + ls[3 * ND + d];
        float Q = lq[d] + lq[ND + d] + lq[2 * ND + d] + lq[3 * ND + d];
        part3[blockIdx.x * (2 * ND) + d] = S;
        part3[blockIdx.x * (2 * ND) + ND + d] = Q;
    }
}

// ---------------- K4: finish variance -> scale = gamma/(sqrt(var+eps)+eps)
__global__ __launch_bounds__(128) void k4(const float* __restrict__ part3,
                                          const float* __restrict__ gamma,
                                          float* __restrict__ scaleG) {
    const int d = threadIdx.x;
    double S = 0.0, Q = 0.0;
    for (int b = 0; b < NBLK; ++b) {
        S += (double)part3[b * (2 * ND) + d];
        Q += (double)part3[b * (2 * ND) + ND + d];
    }
    const double N = (double)NPTS;
    double mu = S / N;
    double var = Q / N - mu * mu;
    if (var < 0.0) var = 0.0;
    float stdv = sqrtf((float)var + EPSV);
    scaleG[d] = gamma[d] / (stdv + EPSV);
}

// ---------------- K5: recompute x_T, scale, rescale, transp0(beta), expmap(beta)
__global__ __launch_bounds__(256) void k5(const float2* __restrict__ x2,
                                          const float* __restrict__ meanG,
                                          const float* __restrict__ scaleG,
                                          const float* __restrict__ betaG,
                                          float2* __restrict__ out2) {
    const int l = threadIdx.x & 63;
    const int w = threadIdx.x >> 6;
    const float2 m = ((const float2*)meanG)[l];
    const float m0 = meanG[0];
    const float2 sc = ((const float2*)scaleG)[l];
    const float2 bt = ((const float2*)betaG)[l];
    const float b0 = betaG[0];
    const long long base = (long long)blockIdx.x * PPB;
    for (int i = 0; i < PPB / 4; ++i) {
        long long p = base + (long long)i * 4 + w;
        float2 xv = x2[p * 64 + l];
        float t0, t1;
        tangent_at_origin(xv, m, m0, l, t0, t1);
        // gamma / (std + eps)
        t0 *= sc.x; t1 *= sc.y;
        // rescale to max euclid norm 32
        float nsq = wred(t0 * t0 + t1 * t1);
        float n = sqrtf(nsq);
        float r = fminf(1.f, MAXEUC / fmaxf(n, CLAMPV));
        t0 *= r; t1 *= r;
        // transp0(beta): coef = <beta,v>_L/(1+beta0); v += coef*(beta + origin)
        float bdot = wred(bt.x * t0 + bt.y * t1);
        float vt = __shfl(t0, 0, 64);
        float coef = (bdot - 2.f * b0 * vt) / (1.f + b0);
        t0 += coef * (bt.x + ((l == 0) ? 1.f : 0.f));
        t1 += coef * bt.y;
        // expmap at beta
        float vv = wred(t0 * t0 + t1 * t1);
        float vt2 = __shfl(t0, 0, 64);
        vv -= 2.f * vt2 * vt2;                       // <u,u>_L
        float nu = sqrtf(fmaxf(vv, CLAMPV));
        float ch = coshf(nu);
        float sf = sinhf(nu) / nu;
        float o0 = ch * bt.x + sf * t0;
        float o1 = ch * bt.y + sf * t1;
        out2[p * 64 + l] = make_float2(o0, o1);
    }
}

extern "C" void kernel_launch(void* const* d_in, const int* in_sizes, int n_in,
                              void* d_out, int out_size, void* d_ws, size_t ws_size,
                              hipStream_t stream) {
    const float* x = (const float*)d_in[0];
    const float* gamma = (const float*)d_in[1];
    const float* beta = (const float*)d_in[2];
    float* out = (float*)d_out;
    float* ws = (float*)d_ws;

    // ws layout (floats):
    float* part1  = ws;                       // 64*8*128  = 65536
    float* meanG  = ws + 65536;               // 128
    float* scaleG = ws + 65536 + 128;         // 128
    float* part3  = ws + 65536 + 256;         // NBLK*256 = 262144

    k1<<<NB * 8, 256, 0, stream>>>((const float4*)x, (float4*)part1);
    k2<<<1, 256, 0, stream>>>(part1, meanG);
    k3<<<NBLK, 256, 0, stream>>>((const float2*)x, meanG, part3);
    k4<<<1, 128, 0, stream>>>(part3, gamma, scaleG);
    k5<<<NBLK, 256, 0, stream>>>((const float2*)x, meanG, scaleG, beta, (float2*)out);
}

// Round 2
// 324.910 us; speedup vs baseline: 1.8231x; 1.8231x over previous
//
#include <hip/hip_runtime.h>
#include <math.h>

// Problem constants (from setup_inputs): B=64, S=4096, D=128.
#define NB 64
#define NS 4096
#define ND 128
#define NPTS (NB * NS)          // 262144 points
#define PPB 256                 // points per block in K3/K5
#define NBLK (NPTS / PPB)       // 1024 blocks
#define EPSV 1e-5f
#define CLAMPV 1e-8f
#define MAXEUC 32.0f

__device__ __forceinline__ float rcp_f(float x) { return __builtin_amdgcn_rcpf(x); }
__device__ __forceinline__ float rsq_f(float x) { return __builtin_amdgcn_rsqf(x); }

// 5-step butterfly within each 32-lane half (2 points per wave)
__device__ __forceinline__ float hred(float v) {
#pragma unroll
    for (int o = 16; o > 0; o >>= 1) v += __shfl_xor(v, o, 64);
    return v;
}

// ---------------- K1: partial sums of x over S (per b, per chunk of 512 rows)
__global__ __launch_bounds__(256) void k1(const float4* __restrict__ x4,
                                          float4* __restrict__ part1) {
    const int b = blockIdx.x >> 3;
    const int c = blockIdx.x & 7;
    const int d4 = threadIdx.x & 31;
    const int g  = threadIdx.x >> 5;
    const int srow = c * 512 + g;
    const float4* p = x4 + ((long long)b * NS + srow) * 32 + d4;
    float4 acc = make_float4(0.f, 0.f, 0.f, 0.f);
#pragma unroll 4
    for (int i = 0; i < 64; ++i) {
        float4 v = p[(long long)i * 8 * 32];
        acc.x += v.x; acc.y += v.y; acc.z += v.z; acc.w += v.w;
    }
    __shared__ float4 red[256];
    red[threadIdx.x] = acc;
    __syncthreads();
    if (threadIdx.x < 32) {
        float4 r = red[threadIdx.x];
#pragma unroll
        for (int gg = 1; gg < 8; ++gg) {
            float4 v = red[gg * 32 + threadIdx.x];
            r.x += v.x; r.y += v.y; r.z += v.z; r.w += v.w;
        }
        part1[(long long)blockIdx.x * 32 + threadIdx.x] = r;
    }
}

// ---------------- K2: double Lorentz centroid -> mean (D,)
__global__ __launch_bounds__(1024) void k2(const float* __restrict__ part1,
                                           float* __restrict__ meanG) {
    __shared__ float avgL[NB * ND];
    __shared__ float avg2L[ND];
    __shared__ float denomS;
    const int t = threadIdx.x;
    for (int idx = t; idx < NB * ND; idx += 1024) {
        int b = idx >> 7, d = idx & 127;
        float s = 0.f;
#pragma unroll
        for (int c = 0; c < 8; ++c) s += part1[((b << 3) + c) * ND + d];
        avgL[idx] = s * (1.0f / (float)NS);
    }
    __syncthreads();
    const int w = t >> 6, l = t & 63;
    for (int b = w; b < NB; b += 16) {
        float a0 = avgL[b * ND + l];
        float a1 = avgL[b * ND + 64 + l];
        float a00 = avgL[b * ND];
        float s = a0 * a0 + a1 * a1;
#pragma unroll
        for (int o = 32; o > 0; o >>= 1) s += __shfl_xor(s, o, 64);
        float denom = sqrtf(fmaxf(2.f * a00 * a00 - s, CLAMPV));
        avgL[b * ND + l] = a0 / denom;
        avgL[b * ND + 64 + l] = a1 / denom;
    }
    __syncthreads();
    if (t < ND) {
        float s = 0.f;
        for (int b = 0; b < NB; ++b) s += avgL[b * ND + t];
        avg2L[t] = s * (1.0f / (float)NB);
    }
    __syncthreads();
    if (w == 0) {
        float a0 = avg2L[l], a1 = avg2L[l + 64];
        float s = a0 * a0 + a1 * a1;
#pragma unroll
        for (int o = 32; o > 0; o >>= 1) s += __shfl_xor(s, o, 64);
        float a00 = avg2L[0];
        float denom = sqrtf(fmaxf(2.f * a00 * a00 - s, CLAMPV));
        if (l == 0) denomS = denom;
    }
    __syncthreads();
    if (t < ND) meanG[t] = avg2L[t] / denomS;
}

// Per-point scalars for the collapsed logmap+transp0back:
//   t_d = fac*x_d + hcoef*m_d  (d>=1),  t_0 = 0 exactly.
// alpha = clip(2*m0*x0 - dot(m,x), 1+1e-7); uu = alpha^2-1 (hyperboloid identity);
// fac = acosh(alpha)/sqrt(uu); hcoef = -fac*(alpha + u0/(1+m0)), u0 = x0 - alpha*m0.
__device__ __forceinline__ void point_scalars(const float4& xv, const float4& m,
                                              float m0, float inv1pm0, int l,
                                              float& fac, float& hcoef) {
    float dot = xv.x * m.x + xv.y * m.y + xv.z * m.z + xv.w * m.w;
    dot = hred(dot);
    float x0 = __shfl(xv.x, l & 32, 64);
    float alpha = fmaxf(2.f * m0 * x0 - dot, 1.0f + 1e-7f);
    float am1 = alpha * alpha - 1.f;
    float sq = sqrtf(fmaxf(am1, CLAMPV));
    fac = __logf(alpha + sq) * rcp_f(sq);          // acosh(alpha)/unorm
    float u0 = x0 - alpha * m0;
    hcoef = -fac * (alpha + u0 * inv1pm0);
}

// ---------------- K3: per-feature sum and sumsq of x_T (per-block partials)
__global__ __launch_bounds__(256) void k3(const float4* __restrict__ x4,
                                          const float* __restrict__ meanG,
                                          float* __restrict__ part3) {
    const int l = threadIdx.x & 63;
    const int w = threadIdx.x >> 6;
    const int h = l >> 5;
    const int fl = l & 31;
    const float4 m = ((const float4*)meanG)[fl];
    const float m0 = meanG[0];
    const float inv1pm0 = rcp_f(1.f + m0);
    float4 s = make_float4(0.f, 0.f, 0.f, 0.f);
    float4 q = make_float4(0.f, 0.f, 0.f, 0.f);
    const long long base = (long long)blockIdx.x * PPB;
#pragma unroll 4
    for (int i = 0; i < PPB / 8; ++i) {           // 8 points per block-iter
        long long p = base + (long long)i * 8 + (w << 1) + h;
        float4 xv = x4[p * 32 + fl];
        float fac, hc;
        point_scalars(xv, m, m0, inv1pm0, l, fac, hc);
        float t0 = fac * xv.x + hc * m.x;
        float t1 = fac * xv.y + hc * m.y;
        float t2 = fac * xv.z + hc * m.z;
        float t3 = fac * xv.w + hc * m.w;
        if (fl == 0) t0 = 0.f;                    // time component is exactly 0
        s.x += t0; s.y += t1; s.z += t2; s.w += t3;
        q.x += t0 * t0; q.y += t1 * t1; q.z += t2 * t2; q.w += t3 * t3;
    }
    __shared__ float4 ls[8][32];
    __shared__ float4 lq[8][32];
    const int copy = (w << 1) + h;
    ls[copy][fl] = s;
    lq[copy][fl] = q;
    __syncthreads();
    if (threadIdx.x < ND) {
        int d = threadIdx.x;
        const float* lsf = (const float*)ls;
        const float* lqf = (const float*)lq;
        float S = 0.f, Q = 0.f;
#pragma unroll
        for (int cc = 0; cc < 8; ++cc) { S += lsf[cc * ND + d]; Q += lqf[cc * ND + d]; }
        part3[blockIdx.x * (2 * ND) + d] = S;
        part3[blockIdx.x * (2 * ND) + ND + d] = Q;
    }
}

// ---------------- K4: finish variance -> scale = gamma/(sqrt(var+eps)+eps)
__global__ __launch_bounds__(1024) void k4(const float* __restrict__ part3,
                                           const float* __restrict__ gamma,
                                           float* __restrict__ scaleG) {
    const int t = threadIdx.x;
    const int d = t & 127, g = t >> 7;            // 8 groups
    double S = 0.0, Q = 0.0;
    for (int b = g; b < NBLK; b += 8) {
        S += (double)part3[b * (2 * ND) + d];
        Q += (double)part3[b * (2 * ND) + ND + d];
    }
    __shared__ double sS[8][ND];
    __shared__ double sQ[8][ND];
    sS[g][d] = S; sQ[g][d] = Q;
    __syncthreads();
    if (t < ND) {
        double St = 0.0, Qt = 0.0;
#pragma unroll
        for (int gg = 0; gg < 8; ++gg) { St += sS[gg][d]; Qt += sQ[gg][d]; }
        const double N = (double)NPTS;
        double mu = St / N;
        double var = Qt / N - mu * mu;
        if (var < 0.0) var = 0.0;
        float stdv = sqrtf((float)var + EPSV);
        scaleG[d] = gamma[d] / (stdv + EPSV);
    }
}

// ---------------- K5: recompute x_T, scale, rescale, transp0(beta), expmap(beta)
__global__ __launch_bounds__(256) void k5(const float4* __restrict__ x4,
                                          const float* __restrict__ meanG,
                                          const float* __restrict__ scaleG,
                                          const float* __restrict__ betaG,
                                          float4* __restrict__ out4) {
    const int l = threadIdx.x & 63;
    const int w = threadIdx.x >> 6;
    const int h = l >> 5;
    const int fl = l & 31;
    const float4 m  = ((const float4*)meanG)[fl];
    const float4 sc = ((const float4*)scaleG)[fl];
    const float4 bt = ((const float4*)betaG)[fl];
    const float m0 = meanG[0];
    const float b0 = betaG[0];
    const float inv1pm0 = rcp_f(1.f + m0);
    const float inv1pb0 = rcp_f(1.f + b0);
    const long long base = (long long)blockIdx.x * PPB;
#pragma unroll 4
    for (int i = 0; i < PPB / 8; ++i) {
        long long p = base + (long long)i * 8 + (w << 1) + h;
        float4 xv = x4[p * 32 + fl];
        float fac, hc;
        point_scalars(xv, m, m0, inv1pm0, l, fac, hc);
        // scaled tangent-at-origin: ts_d = sc_d*(fac*x_d + hc*m_d); ts_0 = 0
        float ts0 = sc.x * (fac * xv.x + hc * m.x);
        float ts1 = sc.y * (fac * xv.y + hc * m.y);
        float ts2 = sc.z * (fac * xv.z + hc * m.z);
        float ts3 = sc.w * (fac * xv.w + hc * m.w);
        if (fl == 0) ts0 = 0.f;
        // fused reductions: nn = ||ts||^2 ; bd = <beta_s, ts_s> (pre-rescale)
        float nn = ts0 * ts0 + ts1 * ts1 + ts2 * ts2 + ts3 * ts3;
        float bd = bt.x * ts0 + bt.y * ts1 + bt.z * ts2 + bt.w * ts3;
#pragma unroll
        for (int o = 16; o > 0; o >>= 1) {
            nn += __shfl_xor(nn, o, 64);
            bd += __shfl_xor(bd, o, 64);
        }
        float n = sqrtf(nn);
        float r = fminf(1.f, MAXEUC * rcp_f(fmaxf(n, CLAMPV)));
        // transp0(beta): v' = r*ts + coef2*(beta+o), coef2 = r*bd/(1+b0)
        float coef2 = r * bd * inv1pb0;
        // expmap at beta: <v',v'>_L = (r*n)^2 (transport preserves Lorentz norm; v0=0)
        float nu2 = r * n; nu2 *= nu2;
        float nu = sqrtf(fmaxf(nu2, CLAMPV));
        float e = __expf(nu);
        float ei = rcp_f(e);
        float ch = 0.5f * (e + ei);
        float sf = (0.5f * (e - ei)) * rcp_f(nu);  // sinh(nu)/nu
        float A = ch + sf * coef2;
        float Bc = sf * r;
        float o0 = Bc * ts0 + A * bt.x;
        float o1 = Bc * ts1 + A * bt.y;
        float o2 = Bc * ts2 + A * bt.z;
        float o3 = Bc * ts3 + A * bt.w;
        if (fl == 0) o0 += sf * coef2;             // the "+o" in (beta+o), time slot
        out4[p * 32 + fl] = make_float4(o0, o1, o2, o3);
    }
}

extern "C" void kernel_launch(void* const* d_in, const int* in_sizes, int n_in,
                              void* d_out, int out_size, void* d_ws, size_t ws_size,
                              hipStream_t stream) {
    const float* x = (const float*)d_in[0];
    const float* gamma = (const float*)d_in[1];
    const float* beta = (const float*)d_in[2];
    float* out = (float*)d_out;
    float* ws = (float*)d_ws;

    float* part1  = ws;                       // 64*8*128  = 65536
    float* meanG  = ws + 65536;               // 128
    float* scaleG = ws + 65536 + 128;         // 128
    float* part3  = ws + 65536 + 256;         // NBLK*256 = 262144

    k1<<<NB * 8, 256, 0, stream>>>((const float4*)x, (float4*)part1);
    k2<<<1, 1024, 0, stream>>>(part1, meanG);
    k3<<<NBLK, 256, 0, stream>>>((const float4*)x, meanG, part3);
    k4<<<1, 1024, 0, stream>>>(part3, gamma, scaleG);
    k5<<<NBLK, 256, 0, stream>>>((const float4*)x, meanG, scaleG, beta, (float4*)out);
}

// Round 3
// 319.935 us; speedup vs baseline: 1.8514x; 1.0155x over previous
//
#include <hip/hip_runtime.h>
#include <math.h>

// Problem constants (from setup_inputs): B=64, S=4096, D=128.
#define NB 64
#define NS 4096
#define ND 128
#define NPTS (NB * NS)          // 262144 points
#define PPB 256                 // points per block in K3/K5
#define NBLK (NPTS / PPB)       // 1024 blocks
#define EPSV 1e-5f
#define CLAMPV 1e-8f
#define MAXEUC 32.0f

__device__ __forceinline__ float rcp_f(float x) { return __builtin_amdgcn_rcpf(x); }

// v += row_ror(v, N) — full-rate VALU DPP, no LDS pipe.
#define DPP_ADD(v, ctrl)                                                            \
    v += __int_as_float(__builtin_amdgcn_update_dpp(0, __float_as_int(v), (ctrl),   \
                                                    0xF, 0xF, true))

// Sum across each 16-lane row; every lane of the row gets the total.
__device__ __forceinline__ float row16_sum(float v) {
    DPP_ADD(v, 0x128);  // ror:8
    DPP_ADD(v, 0x124);  // ror:4
    DPP_ADD(v, 0x122);  // ror:2
    DPP_ADD(v, 0x121);  // ror:1
    return v;
}

// ---------------- K1: partial sums of x over S (per b, per chunk of 512 rows)
__global__ __launch_bounds__(256) void k1(const float4* __restrict__ x4,
                                          float4* __restrict__ part1) {
    const int b = blockIdx.x >> 3;
    const int c = blockIdx.x & 7;
    const int d4 = threadIdx.x & 31;
    const int g  = threadIdx.x >> 5;
    const int srow = c * 512 + g;
    const float4* p = x4 + ((long long)b * NS + srow) * 32 + d4;
    float4 acc = make_float4(0.f, 0.f, 0.f, 0.f);
#pragma unroll 4
    for (int i = 0; i < 64; ++i) {
        float4 v = p[(long long)i * 8 * 32];
        acc.x += v.x; acc.y += v.y; acc.z += v.z; acc.w += v.w;
    }
    __shared__ float4 red[256];
    red[threadIdx.x] = acc;
    __syncthreads();
    if (threadIdx.x < 32) {
        float4 r = red[threadIdx.x];
#pragma unroll
        for (int gg = 1; gg < 8; ++gg) {
            float4 v = red[gg * 32 + threadIdx.x];
            r.x += v.x; r.y += v.y; r.z += v.z; r.w += v.w;
        }
        part1[(long long)blockIdx.x * 32 + threadIdx.x] = r;
    }
}

// ---------------- K2: double Lorentz centroid -> mean (D,)
__global__ __launch_bounds__(1024) void k2(const float* __restrict__ part1,
                                           float* __restrict__ meanG) {
    __shared__ float avgL[NB * ND];
    __shared__ float avg2L[ND];
    __shared__ float denomS;
    const int t = threadIdx.x;
    for (int idx = t; idx < NB * ND; idx += 1024) {
        int b = idx >> 7, d = idx & 127;
        float s = 0.f;
#pragma unroll
        for (int c = 0; c < 8; ++c) s += part1[((b << 3) + c) * ND + d];
        avgL[idx] = s * (1.0f / (float)NS);
    }
    __syncthreads();
    const int w = t >> 6, l = t & 63;
    for (int b = w; b < NB; b += 16) {
        float a0 = avgL[b * ND + l];
        float a1 = avgL[b * ND + 64 + l];
        float a00 = avgL[b * ND];
        float s = a0 * a0 + a1 * a1;
#pragma unroll
        for (int o = 32; o > 0; o >>= 1) s += __shfl_xor(s, o, 64);
        float denom = sqrtf(fmaxf(2.f * a00 * a00 - s, CLAMPV));
        avgL[b * ND + l] = a0 / denom;
        avgL[b * ND + 64 + l] = a1 / denom;
    }
    __syncthreads();
    if (t < ND) {
        float s = 0.f;
        for (int b = 0; b < NB; ++b) s += avgL[b * ND + t];
        avg2L[t] = s * (1.0f / (float)NB);
    }
    __syncthreads();
    if (w == 0) {
        float a0 = avg2L[l], a1 = avg2L[l + 64];
        float s = a0 * a0 + a1 * a1;
#pragma unroll
        for (int o = 32; o > 0; o >>= 1) s += __shfl_xor(s, o, 64);
        float a00 = avg2L[0];
        float denom = sqrtf(fmaxf(2.f * a00 * a00 - s, CLAMPV));
        if (l == 0) denomS = denom;
    }
    __syncthreads();
    if (t < ND) meanG[t] = avg2L[t] / denomS;
}

// Per-point scalars, 16-lane-per-point layout. Lane fl holds x float4s a,b.
// alpha = clip(2 m0 x0 - dot(m,x), 1+1e-7)  via weighted dot (weight +m0 on slot0)
// fac = acosh(alpha)/sqrt(alpha^2-1);  hcoef = -fac*(alpha+x0)/(1+m0)
__device__ __forceinline__ void point_scalars16(const float4& xa, const float4& xb,
                                                const float4& wa, const float4& wb,
                                                float m0, float inv1pm0, int fl,
                                                float& fac, float& hcoef) {
    float ad = wa.x * xa.x + wa.y * xa.y + wa.z * xa.z + wa.w * xa.w
             + wb.x * xb.x + wb.y * xb.y + wb.z * xb.z + wb.w * xb.w;
    float px = (fl == 0) ? xa.x : 0.f;
    ad = row16_sum(ad);          // = 2 m0 x0 - dot(m,x)
    px = row16_sum(px);          // = x0
    float alpha = fmaxf(ad, 1.0f + 1e-7f);
    float am1 = alpha * alpha - 1.f;
    float sq = sqrtf(fmaxf(am1, CLAMPV));
    fac = __logf(alpha + sq) * rcp_f(sq);           // acosh(alpha)/unorm
    hcoef = -fac * (alpha + px) * inv1pm0;
}

// ---------------- K3: per-feature sum and sumsq of x_T (per-block partials)
__global__ __launch_bounds__(256) void k3(const float4* __restrict__ x4,
                                          const float* __restrict__ meanG,
                                          float* __restrict__ part3) {
    const int fl = threadIdx.x & 15;     // slot within point
    const int pg = threadIdx.x >> 4;     // point-group within block (0..15)
    const float4* m4 = (const float4*)meanG;
    const float4 ma = m4[fl], mb = m4[fl + 16];
    const float m0 = meanG[0];
    const float inv1pm0 = rcp_f(1.f + m0);
    float4 wa = make_float4(-ma.x, -ma.y, -ma.z, -ma.w);
    float4 wb = make_float4(-mb.x, -mb.y, -mb.z, -mb.w);
    if (fl == 0) wa.x = ma.x;            // weight +m0 on the time slot
    float4 sa = make_float4(0.f, 0.f, 0.f, 0.f), sb = sa, qa = sa, qb = sa;
    const long long base = (long long)blockIdx.x * PPB;
#pragma unroll 4
    for (int i = 0; i < PPB / 16; ++i) {  // 16 points per block-iter
        long long p = base + (long long)i * 16 + pg;
        float4 xa = x4[p * 32 + fl];
        float4 xb = x4[p * 32 + fl + 16];
        float fac, hc;
        point_scalars16(xa, xb, wa, wb, m0, inv1pm0, fl, fac, hc);
        float t0 = fac * xa.x + hc * ma.x;
        float t1 = fac * xa.y + hc * ma.y;
        float t2 = fac * xa.z + hc * ma.z;
        float t3 = fac * xa.w + hc * ma.w;
        float t4 = fac * xb.x + hc * mb.x;
        float t5 = fac * xb.y + hc * mb.y;
        float t6 = fac * xb.z + hc * mb.z;
        float t7 = fac * xb.w + hc * mb.w;
        if (fl == 0) t0 = 0.f;           // time component exactly 0
        sa.x += t0; sa.y += t1; sa.z += t2; sa.w += t3;
        sb.x += t4; sb.y += t5; sb.z += t6; sb.w += t7;
        qa.x += t0 * t0; qa.y += t1 * t1; qa.z += t2 * t2; qa.w += t3 * t3;
        qb.x += t4 * t4; qb.y += t5 * t5; qb.z += t6 * t6; qb.w += t7 * t7;
    }
    // block reduction: ls[copy][fl*8 + j], j=0..3 -> dims 4fl+j, j=4..7 -> 64+4fl+j-4
    __shared__ float ls[16][ND];
    __shared__ float lq[16][ND];
    float* ps = &ls[pg][fl * 8];
    float* pq = &lq[pg][fl * 8];
    ps[0] = sa.x; ps[1] = sa.y; ps[2] = sa.z; ps[3] = sa.w;
    ps[4] = sb.x; ps[5] = sb.y; ps[6] = sb.z; ps[7] = sb.w;
    pq[0] = qa.x; pq[1] = qa.y; pq[2] = qa.z; pq[3] = qa.w;
    pq[4] = qb.x; pq[5] = qb.y; pq[6] = qb.z; pq[7] = qb.w;
    __syncthreads();
    if (threadIdx.x < ND) {
        int d = threadIdx.x;
        int slot = ((d & 63) >> 2) * 8 + (d >> 6) * 4 + (d & 3);
        float S = 0.f, Q = 0.f;
#pragma unroll
        for (int cc = 0; cc < 16; ++cc) { S += ls[cc][slot]; Q += lq[cc][slot]; }
        part3[blockIdx.x * (2 * ND) + d] = S;
        part3[blockIdx.x * (2 * ND) + ND + d] = Q;
    }
}

// ---------------- K4: finish variance -> scale = gamma/(sqrt(var+eps)+eps)
__global__ __launch_bounds__(1024) void k4(const float* __restrict__ part3,
                                           const float* __restrict__ gamma,
                                           float* __restrict__ scaleG) {
    const int t = threadIdx.x;
    const int d = t & 127, g = t >> 7;            // 8 groups
    double S = 0.0, Q = 0.0;
    for (int b = g; b < NBLK; b += 8) {
        S += (double)part3[b * (2 * ND) + d];
        Q += (double)part3[b * (2 * ND) + ND + d];
    }
    __shared__ double sS[8][ND];
    __shared__ double sQ[8][ND];
    sS[g][d] = S; sQ[g][d] = Q;
    __syncthreads();
    if (t < ND) {
        double St = 0.0, Qt = 0.0;
#pragma unroll
        for (int gg = 0; gg < 8; ++gg) { St += sS[gg][d]; Qt += sQ[gg][d]; }
        const double N = (double)NPTS;
        double mu = St / N;
        double var = Qt / N - mu * mu;
        if (var < 0.0) var = 0.0;
        float stdv = sqrtf((float)var + EPSV);
        scaleG[d] = gamma[d] / (stdv + EPSV);
    }
}

// ---------------- K5: recompute x_T, scale, rescale, transp0(beta), expmap(beta)
__global__ __launch_bounds__(256) void k5(const float4* __restrict__ x4,
                                          const float* __restrict__ meanG,
                                          const float* __restrict__ scaleG,
                                          const float* __restrict__ betaG,
                                          float4* __restrict__ out4) {
    const int fl = threadIdx.x & 15;
    const int pg = threadIdx.x >> 4;
    const float4* m4 = (const float4*)meanG;
    const float4* s4 = (const float4*)scaleG;
    const float4* b4 = (const float4*)betaG;
    const float4 ma = m4[fl], mb = m4[fl + 16];
    const float4 sca = s4[fl], scb = s4[fl + 16];
    const float4 bta = b4[fl], btb = b4[fl + 16];
    const float m0 = meanG[0];
    const float b0 = betaG[0];
    const float inv1pm0 = rcp_f(1.f + m0);
    const float inv1pb0 = rcp_f(1.f + b0);
    float4 wa = make_float4(-ma.x, -ma.y, -ma.z, -ma.w);
    float4 wb = make_float4(-mb.x, -mb.y, -mb.z, -mb.w);
    if (fl == 0) wa.x = ma.x;
    const long long base = (long long)blockIdx.x * PPB;
#pragma unroll 4
    for (int i = 0; i < PPB / 16; ++i) {
        long long p = base + (long long)i * 16 + pg;
        float4 xa = x4[p * 32 + fl];
        float4 xb = x4[p * 32 + fl + 16];
        float fac, hc;
        point_scalars16(xa, xb, wa, wb, m0, inv1pm0, fl, fac, hc);
        // scaled tangent-at-origin
        float ts0 = sca.x * (fac * xa.x + hc * ma.x);
        float ts1 = sca.y * (fac * xa.y + hc * ma.y);
        float ts2 = sca.z * (fac * xa.z + hc * ma.z);
        float ts3 = sca.w * (fac * xa.w + hc * ma.w);
        float ts4 = scb.x * (fac * xb.x + hc * mb.x);
        float ts5 = scb.y * (fac * xb.y + hc * mb.y);
        float ts6 = scb.z * (fac * xb.z + hc * mb.z);
        float ts7 = scb.w * (fac * xb.w + hc * mb.w);
        if (fl == 0) ts0 = 0.f;
        // fused reductions: nn = ||ts||^2 ; bd = <beta_s, ts_s> (pre-rescale)
        float nn = ts0 * ts0 + ts1 * ts1 + ts2 * ts2 + ts3 * ts3
                 + ts4 * ts4 + ts5 * ts5 + ts6 * ts6 + ts7 * ts7;
        float bd = bta.x * ts0 + bta.y * ts1 + bta.z * ts2 + bta.w * ts3
                 + btb.x * ts4 + btb.y * ts5 + btb.z * ts6 + btb.w * ts7;
        nn = row16_sum(nn);
        bd = row16_sum(bd);
        float n = sqrtf(nn);
        float r = fminf(1.f, MAXEUC * rcp_f(fmaxf(n, CLAMPV)));
        float coef2 = r * bd * inv1pb0;            // transp0(beta) coefficient
        float nu = fmaxf(r * n, 1e-4f);            // sqrt(clip((r n)^2, 1e-8))
        float e = __expf(nu);
        float ei = rcp_f(e);
        float ch = 0.5f * (e + ei);
        float sf = (0.5f * (e - ei)) * rcp_f(nu);  // sinh(nu)/nu
        float A = ch + sf * coef2;
        float Bc = sf * r;
        float4 oa, ob;
        oa.x = Bc * ts0 + A * bta.x;
        oa.y = Bc * ts1 + A * bta.y;
        oa.z = Bc * ts2 + A * bta.z;
        oa.w = Bc * ts3 + A * bta.w;
        ob.x = Bc * ts4 + A * btb.x;
        ob.y = Bc * ts5 + A * btb.y;
        ob.z = Bc * ts6 + A * btb.z;
        ob.w = Bc * ts7 + A * btb.w;
        if (fl == 0) oa.x += sf * coef2;           // the "+o" time slot
        out4[p * 32 + fl] = oa;
        out4[p * 32 + fl + 16] = ob;
    }
}

extern "C" void kernel_launch(void* const* d_in, const int* in_sizes, int n_in,
                              void* d_out, int out_size, void* d_ws, size_t ws_size,
                              hipStream_t stream) {
    const float* x = (const float*)d_in[0];
    const float* gamma = (const float*)d_in[1];
    const float* beta = (const float*)d_in[2];
    float* out = (float*)d_out;
    float* ws = (float*)d_ws;

    float* part1  = ws;                       // 64*8*128  = 65536 floats
    float* meanG  = ws + 65536;               // 128
    float* scaleG = ws + 65536 + 128;         // 128
    float* part3  = ws + 65536 + 256;         // NBLK*256 = 262144

    k1<<<NB * 8, 256, 0, stream>>>((const float4*)x, (float4*)part1);
    k2<<<1, 1024, 0, stream>>>(part1, meanG);
    k3<<<NBLK, 256, 0, stream>>>((const float4*)x, meanG, part3);
    k4<<<1, 1024, 0, stream>>>(part3, gamma, scaleG);
    k5<<<NBLK, 256, 0, stream>>>((const float4*)x, meanG, scaleG, beta, (float4*)out);
}